// Round 8
// baseline (97.888 us; speedup 1.0000x reference)
//
#include <hip/hip_runtime.h>
#include <math.h>

#define B 1024
#define O 256
#define D 1024
#define ALPHA 0.005f

#define RPB 8            // b rows per block -> c L2 traffic ~13 TB/s at full VALU speed
#define DS  16           // D splits -> 2048 blocks -> 8 blocks/CU
#define DCH (D / DS)     // 64 d per slice
#define CH  4            // d per chunk: c = 1 float4/lane, x = 8 s_load_dwordx4 (uniform)
#define NCH (DCH / CH)   // 16 chunks

// Kernel 0: transpose c[O][D] -> ct[D/4][O] (float4) for coalesced c loads (1 MB).
__global__ __launch_bounds__(256) void transpose_c(const float* __restrict__ c,
                                                   float4* __restrict__ ct)
{
    const int o  = threadIdx.x;         // 0..255
    const int d4 = blockIdx.x;          // 0..D/4-1
    const float* src = c + (size_t)o * D + d4 * 4;
    ct[(size_t)d4 * O + o] = make_float4(src[0], src[1], src[2], src[3]);
}

// Kernel 1: lane -> centroid o (coalesced float4 c loads from ct).
// The block's 8 x rows are wave-uniform; x is indexed by a single flat
// all-uniform expression (no pointer arrays) so the backend can prove
// uniformity and emit s_load into SGPRs (scalar pipe, costs no VMEM issue).
// 96 VALU ops per chunk cover the single c VMEM load; 8 blocks/CU of TLP.
__global__ __launch_bounds__(256) void dist_part(const float* __restrict__ x,
                                                 const float4* __restrict__ ct,
                                                 float* __restrict__ s1p,
                                                 float* __restrict__ s2p)
{
    const int o  = threadIdx.x;               // centroid (per-lane)
    const int b0 = blockIdx.x * RPB;          // first b row (uniform)
    const int ds = blockIdx.y;                // d-slice (uniform)
    const int d0 = ds * DCH;

    const float4* cts = ct + (size_t)(d0 / 4) * O + o;   // step O float4 per d4

    float s1[RPB], s2[RPB];
    #pragma unroll
    for (int i = 0; i < RPB; ++i) { s1[i] = 0.f; s2[i] = 0.f; }

    float4 cA, cB;                        // per-lane c chunk
    float  xA[RPB][CH], xB[RPB][CH];      // wave-uniform x chunk (SGPRs)

#define LOADC(BUF, CHIDX)  { BUF = cts[(size_t)(CHIDX) * O]; }

#define LOADX(BUF, CHIDX)                                                   \
    { _Pragma("unroll")                                                     \
      for (int bi = 0; bi < RPB; ++bi)                                      \
          _Pragma("unroll")                                                 \
          for (int k = 0; k < CH; ++k)                                      \
              BUF[bi][k] = x[(size_t)(b0 + bi) * D + d0 + (CHIDX) * CH + k]; }

#define COMP(CBUF, XBUF)                                                    \
    { float cv[CH] = {CBUF.x, CBUF.y, CBUF.z, CBUF.w};                      \
      _Pragma("unroll")                                                     \
      for (int bi = 0; bi < RPB; ++bi)                                      \
          _Pragma("unroll")                                                 \
          for (int k = 0; k < CH; ++k) {                                    \
              float dd = XBUF[bi][k] - cv[k];                               \
              s1[bi] += __builtin_fabsf(dd);                                \
              s2[bi] = __builtin_fmaf(dd, dd, s2[bi]);                      \
          } }

    LOADC(cA, 0)
    LOADX(xA, 0)

    for (int ch = 0; ch < NCH; ch += 2) {
        LOADC(cB, ch + 1)
        LOADX(xB, ch + 1)
        COMP(cA, xA)

        const int nch = (ch + 2 < NCH) ? (ch + 2) : (NCH - 1);
        LOADC(cA, nch)
        LOADX(xA, nch)
        COMP(cB, xB)
    }
#undef LOADC
#undef LOADX
#undef COMP

    #pragma unroll
    for (int bi = 0; bi < RPB; ++bi) {
        const size_t idx = ((size_t)ds * B + (b0 + bi)) * O + o;   // coalesced in o
        s1p[idx] = s1[bi];
        s2p[idx] = s2[bi];
    }
}

// Kernel 2: combine D-slices, sqrt + temperature + alpha row-correction.
__global__ __launch_bounds__(256) void combine_kernel(const float* __restrict__ s1p,
                                                      const float* __restrict__ s2p,
                                                      float* __restrict__ out)
{
    const int b = blockIdx.x;
    const int o = threadIdx.x;

    float a1 = 0.f, a2 = 0.f;
    #pragma unroll
    for (int ds = 0; ds < DS; ++ds) {
        const size_t idx = ((size_t)ds * B + b) * O + o;
        a1 += s1p[idx];
        a2 += s2p[idx];
    }
    const float v = a1 + 0.5f * __builtin_sqrtf(a2);

    float t = v;
    #pragma unroll
    for (int off = 32; off >= 1; off >>= 1)
        t += __shfl_down(t, off, 64);

    __shared__ float ws[4];
    if ((o & 63) == 0) ws[o >> 6] = t;
    __syncthreads();
    const float S = ws[0] + ws[1] + ws[2] + ws[3];

    out[(size_t)b * O + o] = ALPHA * S - (1.0f + ALPHA) * v;
}

extern "C" void kernel_launch(void* const* d_in, const int* in_sizes, int n_in,
                              void* d_out, int out_size, void* d_ws, size_t ws_size,
                              hipStream_t stream) {
    const float* x = (const float*)d_in[0];   // [B, D]
    const float* c = (const float*)d_in[1];   // [O, D]
    float* out = (float*)d_out;               // [B, O]

    float*  s1p = (float*)d_ws;                          // [DS, B, O] = 16.8 MB
    float*  s2p = s1p + (size_t)DS * B * O;              // [DS, B, O] = 16.8 MB
    float4* ct  = (float4*)(s2p + (size_t)DS * B * O);   // [D/4, O]   = 1 MB

    transpose_c<<<D / 4, O, 0, stream>>>(c, ct);

    dim3 grid(B / RPB, DS);                   // (128, 16) = 2048 blocks
    dist_part<<<grid, 256, 0, stream>>>(x, ct, s1p, s2p);

    combine_kernel<<<B, 256, 0, stream>>>(s1p, s2p, out);
}